// Round 23
// baseline (136.051 us; speedup 1.0000x reference)
//
#include <hip/hip_runtime.h>
#include <math.h>

#define CT    320
#define NPTS  1024
#define DFEAT 256
#define DPOS  64
#define KSEL  32
#define QSTEP 6.103515625e-05f          // 2^-14, thr(m) = m*QSTEP - 1 (exact)

typedef __attribute__((ext_vector_type(8))) short short8;   // 8 bf16 (4 VGPRs)
typedef __attribute__((ext_vector_type(4))) float f32x4;

__device__ __forceinline__ unsigned bf16_rne(float x) {
  const unsigned u = __float_as_uint(x);
  return (u + 0x7FFFu + ((u >> 16) & 1u)) >> 16;
}
__device__ __forceinline__ float bf16_back(unsigned h) {
  return __uint_as_float(h << 16);
}

// ========== Kernel C2: normalized pos -> transposed bf16x3 planes ==========
// 3-plane split is the PROVEN-safe one (round-21: absmax bit-identical to
// exact). Round-22's 2-plane failed: dropped r*y terms are ~6e-5 (vector
// norm, not per-element) > min rank-32/33 gap over 16K rows.
__global__ __launch_bounds__(256) void gnn_phat(const float* __restrict__ in,
                                                unsigned short* __restrict__ ph0,
                                                unsigned short* __restrict__ ph1,
                                                unsigned short* __restrict__ ph2) {
  const int b     = blockIdx.x;
  const int batch = b >> 2;
  const int j     = ((b & 3) << 8) + threadIdx.x;
  const float* __restrict__ pbase = in + (size_t)batch * CT * NPTS + (size_t)DFEAT * NPTS;

  float x[DPOS];
  float ssq = 0.f;
#pragma unroll
  for (int d = 0; d < DPOS; ++d) {
    x[d] = pbase[(size_t)d * NPTS + j];
    ssq = fmaf(x[d], x[d], ssq);
  }
  const float rn = 1.0f / fmaxf(sqrtf(ssq), 1e-12f);

  const size_t rowoff = ((size_t)batch * NPTS + j) * DPOS;   // elements
  uint4* r0 = (uint4*)(ph0 + rowoff);
  uint4* r1 = (uint4*)(ph1 + rowoff);
  uint4* r2 = (uint4*)(ph2 + rowoff);
#pragma unroll
  for (int qd = 0; qd < 8; ++qd) {
    unsigned a0[8], a1[8], a2[8];
#pragma unroll
    for (int e = 0; e < 8; ++e) {
      const float y = x[qd * 8 + e] * rn;
      a0[e] = bf16_rne(y);
      const float s1 = y - bf16_back(a0[e]);
      a1[e] = bf16_rne(s1);
      const float s2 = s1 - bf16_back(a1[e]);
      a2[e] = bf16_rne(s2);
    }
    uint4 v;
    v.x = a0[0] | (a0[1] << 16); v.y = a0[2] | (a0[3] << 16);
    v.z = a0[4] | (a0[5] << 16); v.w = a0[6] | (a0[7] << 16);
    r0[qd] = v;
    v.x = a1[0] | (a1[1] << 16); v.y = a1[2] | (a1[3] << 16);
    v.z = a1[4] | (a1[5] << 16); v.w = a1[6] | (a1[7] << 16);
    r1[qd] = v;
    v.x = a2[0] | (a2[1] << 16); v.y = a2[2] | (a2[3] << 16);
    v.z = a2[4] | (a2[5] << 16); v.w = a2[6] | (a2[7] << 16);
    r2[qd] = v;
  }
}

// ====== Kernel A: MFMA bf16x3 sim + per-lane topk + merge + softmax ========
// Round-23 = round-21 numerics (proven) + structural fixes: cand = exactly
// 16 KB (4 blocks/CU), afr[4] load grouping (16 VGPR in flight, loads of
// group h+1 overlap MFMAs of group h), bounds(256,4) (acc64+bfr24+afr16+
// misc ~= 124 <= 128).
__global__ __launch_bounds__(256, 4) void gnn_sim_topk(const unsigned short* __restrict__ ph0,
                                                       const unsigned short* __restrict__ ph1,
                                                       const unsigned short* __restrict__ ph2,
                                                       float2* __restrict__ pairs) {
  __shared__ float cand[16][256];      // 16 rows x 128 (v,j) pairs = 16 KB

  const int p     = blockIdx.x;
  const int batch = ((p & 7) << 1) | ((p >> 3) & 1);   // 2 batches per XCD
  const int chunk = p >> 4;            // 0..63
  const int i0    = chunk * 16;
  const int tid   = threadIdx.x;
  const int w     = tid >> 6;
  const int lane  = tid & 63;
  const int il    = lane & 15;
  const int g     = lane >> 4;

  const size_t bb = (size_t)batch * NPTS;

  // B-frags: query rows i0+il, k-slice ks*32 + g*8 .. +7 (3 planes)
  short8 bfr[2][3];
  {
    const size_t off = (bb + i0 + il) * DPOS + g * 8;
#pragma unroll
    for (int ks = 0; ks < 2; ++ks) {
      bfr[ks][0] = *(const short8*)(ph0 + off + ks * 32);
      bfr[ks][1] = *(const short8*)(ph1 + off + ks * 32);
      bfr[ks][2] = *(const short8*)(ph2 + off + ks * 32);
    }
  }

  f32x4 acc[16];
#pragma unroll
  for (int nt = 0; nt < 16; ++nt) acc[nt] = (f32x4){0.f, 0.f, 0.f, 0.f};

  const size_t jo = (bb + w * 256 + il) * DPOS + g * 8;

#pragma unroll
  for (int ks = 0; ks < 2; ++ks) {
#pragma unroll
    for (int h = 0; h < 4; ++h) {      // nt groups of 4: h*4 .. h*4+3
      short8 afr[4];
      // A-plane 0: pairs with B-planes 0,1,2
#pragma unroll
      for (int q = 0; q < 4; ++q)
        afr[q] = *(const short8*)(ph0 + jo + (size_t)(h * 4 + q) * 16 * DPOS + ks * 32);
#pragma unroll
      for (int q = 0; q < 4; ++q)
        acc[h*4+q] = __builtin_amdgcn_mfma_f32_16x16x32_bf16(afr[q], bfr[ks][0], acc[h*4+q], 0, 0, 0);
#pragma unroll
      for (int q = 0; q < 4; ++q)
        acc[h*4+q] = __builtin_amdgcn_mfma_f32_16x16x32_bf16(afr[q], bfr[ks][1], acc[h*4+q], 0, 0, 0);
#pragma unroll
      for (int q = 0; q < 4; ++q)
        acc[h*4+q] = __builtin_amdgcn_mfma_f32_16x16x32_bf16(afr[q], bfr[ks][2], acc[h*4+q], 0, 0, 0);
      // A-plane 1: pairs with B-planes 0,1
#pragma unroll
      for (int q = 0; q < 4; ++q)
        afr[q] = *(const short8*)(ph1 + jo + (size_t)(h * 4 + q) * 16 * DPOS + ks * 32);
#pragma unroll
      for (int q = 0; q < 4; ++q)
        acc[h*4+q] = __builtin_amdgcn_mfma_f32_16x16x32_bf16(afr[q], bfr[ks][0], acc[h*4+q], 0, 0, 0);
#pragma unroll
      for (int q = 0; q < 4; ++q)
        acc[h*4+q] = __builtin_amdgcn_mfma_f32_16x16x32_bf16(afr[q], bfr[ks][1], acc[h*4+q], 0, 0, 0);
      // A-plane 2: pairs with B-plane 0
#pragma unroll
      for (int q = 0; q < 4; ++q)
        afr[q] = *(const short8*)(ph2 + jo + (size_t)(h * 4 + q) * 16 * DPOS + ks * 32);
#pragma unroll
      for (int q = 0; q < 4; ++q)
        acc[h*4+q] = __builtin_amdgcn_mfma_f32_16x16x32_bf16(afr[q], bfr[ks][0], acc[h*4+q], 0, 0, 0);
    }
  }

  // ---- per-lane strip top-32 (row = il; 64 values in acc; rows parallel) ----
  const int jb = w * 256 + g * 4;      // + nt*16 + r
  int lo = 0;
#pragma unroll
  for (int bit = 16384; bit >= 1; bit >>= 1) {
    const float thrf = (float)(lo + bit) * QSTEP - 1.0f;
    int cnt = 0;
#pragma unroll
    for (int nt = 0; nt < 16; ++nt)
#pragma unroll
      for (int r = 0; r < 4; ++r) cnt += (acc[nt][r] >= thrf) ? 1 : 0;
    const int c2 = cnt + __shfl_xor(cnt, 16);
    const int c4 = c2 + __shfl_xor(c2, 32);
    if (c4 >= KSEL) lo += bit;
  }
  const float thr_h = (float)(lo + 1) * QSTEP - 1.0f;
  const float thr_l = (float)lo * QSTEP - 1.0f;

  int lcnt = 0;
#pragma unroll
  for (int nt = 0; nt < 16; ++nt)
#pragma unroll
    for (int r = 0; r < 4; ++r) lcnt += (acc[nt][r] >= thr_h) ? 1 : 0;
  const int cO = __shfl_xor(lcnt, 16);       // count of group g^1
  const int cT = __shfl_xor(lcnt, 32);       // g^2
  const int cH = __shfl_xor(cO, 32);         // g^3
  const int cbase = lcnt + cO + cT + cH;
  const int pre = (g == 0) ? 0 : (g == 1) ? cO : (g == 2) ? (cT + cH) : (cO + cT + cH);

  // definite members -> cand[il][strip slots w*32 + ...]
  {
    int pos = pre;
#pragma unroll
    for (int nt = 0; nt < 16; ++nt) {
#pragma unroll
      for (int r = 0; r < 4; ++r) {
        if (acc[nt][r] >= thr_h) {
          *(float2*)&cand[il][2 * (w * KSEL + pos)] =
              make_float2(acc[nt][r], __int_as_float(jb + nt * 16 + r));
          ++pos;
        }
      }
    }
  }
  // boundary: exact (v desc, j asc); quad-uniform need -> shfl safe
  unsigned long long bm = 0ull;
#pragma unroll
  for (int nt = 0; nt < 16; ++nt)
#pragma unroll
    for (int r = 0; r < 4; ++r)
      if (acc[nt][r] >= thr_l && acc[nt][r] < thr_h) bm |= (1ull << (nt * 4 + r));
  const int need = KSEL - cbase;
  for (int it = 0; it < need; ++it) {
    float bv = -2.0f; int bj = 0x7fffffff; int bs = 0;
#pragma unroll
    for (int nt = 0; nt < 16; ++nt) {
#pragma unroll
      for (int r = 0; r < 4; ++r) {
        if (((bm >> (nt * 4 + r)) & 1ull) && acc[nt][r] > bv) {
          bv = acc[nt][r]; bj = jb + nt * 16 + r; bs = nt * 4 + r;
        }
      }
    }
    float rv = bv; int rj = bj;
    {
      const float ov = __shfl_xor(rv, 16); const int oj = __shfl_xor(rj, 16);
      if (ov > rv || (ov == rv && oj < rj)) { rv = ov; rj = oj; }
    }
    {
      const float ov = __shfl_xor(rv, 32); const int oj = __shfl_xor(rj, 32);
      if (ov > rv || (ov == rv && oj < rj)) { rv = ov; rj = oj; }
    }
    if (bv == rv && bj == rj) {              // unique owner (j unique)
      *(float2*)&cand[il][2 * (w * KSEL + cbase + it)] = make_float2(bv, __int_as_float(bj));
      bm &= ~(1ull << bs);
    }
  }
  __syncthreads();

  // ---- merge 128 -> exact top-32 + softmax; wave w owns rows w*4..w*4+3 ----
#pragma unroll
  for (int rr = 0; rr < 4; ++rr) {
    const int r = w * 4 + rr;
    const float4 c4 = *(const float4*)&cand[r][lane * 4];   // 2 pairs per lane
    float v2[2] = { c4.x, c4.z };
    int   j2[2] = { __float_as_int(c4.y), __float_as_int(c4.w) };
    int lo2 = 0;
#pragma unroll
    for (int bit = 16384; bit >= 1; bit >>= 1) {
      const float thrf = (float)(lo2 + bit) * QSTEP - 1.0f;
      const int cnt = (int)__popcll(__ballot(v2[0] >= thrf)) +
                      (int)__popcll(__ballot(v2[1] >= thrf));
      if (cnt >= KSEL) lo2 += bit;
    }
    const float th = (float)(lo2 + 1) * QSTEP - 1.0f;
    const float tl = (float)lo2 * QSTEP - 1.0f;
    int cb = 0; unsigned cm = 0u;
#pragma unroll
    for (int t = 0; t < 2; ++t) {
      const bool hi = (v2[t] >= th);
      const unsigned long long m = __ballot(hi);
      if (hi) {
        const int ps = cb + (int)__builtin_amdgcn_mbcnt_hi(
            (unsigned)(m >> 32), __builtin_amdgcn_mbcnt_lo((unsigned)m, 0u));
        *(float2*)&cand[r][2 * ps] = make_float2(v2[t], __int_as_float(j2[t]));
      }
      cb += (int)__popcll(m);
      if (v2[t] >= tl && !hi) cm |= (1u << t);
    }
    const int nd = KSEL - cb;
    for (int it = 0; it < nd; ++it) {
      float bv = -2.0f; int bj = 0x7fffffff; int bt = 2;
#pragma unroll
      for (int t = 0; t < 2; ++t) {
        if (((cm >> t) & 1u) && v2[t] > bv) { bv = v2[t]; bj = j2[t]; bt = t; }
      }
      float rv = bv; int rj = bj;
#pragma unroll
      for (int s = 1; s < 64; s <<= 1) {
        const float ov = __shfl_xor(rv, s);
        const int   oj = __shfl_xor(rj, s);
        if (ov > rv || (ov == rv && oj < rj)) { rv = ov; rj = oj; }
      }
      if (bv == rv && bj == rj) {
        *(float2*)&cand[r][2 * (cb + it)] = make_float2(bv, __int_as_float(bj));
        cm &= ~(1u << bt);
      }
    }
    // softmax over the selected 32 (order-invariant)
    {
      const float x = cand[r][2 * (lane & 31)];
      float mx = x;
#pragma unroll
      for (int s = 16; s >= 1; s >>= 1) mx = fmaxf(mx, __shfl_xor(mx, s));
      const float e = expf(x - mx);
      float sum = e;
#pragma unroll
      for (int s = 16; s >= 1; s >>= 1) sum += __shfl_xor(sum, s);
      if (lane < KSEL) cand[r][2 * lane] = e / sum;
    }
  }
  __syncthreads();

  // write (attn, id) pairs: 512 pairs = 256 float4, one per thread
  {
    const int pidx = tid * 2;
    const int r = pidx >> 5, k = pidx & 31;
    const float4 o4 = *(const float4*)&cand[r][2 * k];
    *(float4*)&pairs[((size_t)batch * NPTS + i0 + r) * KSEL + k] = o4;
  }
}

// ====== Kernel B: transposed-LDS float4 gather (round-20 proven, frozen) ====
__global__ __launch_bounds__(256, 2) void gnn_gather(const float* __restrict__ in,
                                                     const float2* __restrict__ pairs,
                                                     float* __restrict__ out) {
  __shared__ float fst[4][4096];       // per-wave 16 KB: 1024 granules x 16B

  const int p     = blockIdx.x;
  const int batch = ((p & 7) << 1) | ((p >> 3) & 1);
  const int chunk = p >> 4;            // 0..31
  const int i0    = chunk * 32;
  const int tid   = threadIdx.x;
  const int w     = tid >> 6;
  const int lane  = tid & 63;
  const int row   = lane & 31;
  const int khalf = lane >> 5;
  const int ch0   = w * 64;

  const float* __restrict__ fbase = in + (size_t)batch * CT * NPTS;
  float* const fw = &fst[w][0];

  float a16[16]; int jjb[16];
  {
    const float4* pr4 = (const float4*)(pairs + ((size_t)batch * NPTS + i0 + row) * KSEL)
                        + khalf * 8;
#pragma unroll
    for (int qq = 0; qq < 8; ++qq) {
      const float4 o = pr4[qq];
      const int id0 = __float_as_int(o.y);
      const int id1 = __float_as_int(o.w);
      a16[2*qq]   = o.x;
      jjb[2*qq]   = ((((id0 & 3) << 6) | ((id0 >> 2) & 63) | (id0 & ~255)) << 4);
      a16[2*qq+1] = o.z;
      jjb[2*qq+1] = ((((id1 & 3) << 6) | ((id1 >> 2) & 63) | (id1 & ~255)) << 4);
    }
  }

  float4 tile[4][4];

#define LOADT(pp)                                                                \
  do {                                                                           \
    _Pragma("unroll")                                                            \
    for (int it = 0; it < 4; ++it) {                                             \
      _Pragma("unroll")                                                          \
      for (int c = 0; c < 4; ++c)                                                \
        tile[it][c] = *(const float4*)(fbase +                                   \
            (size_t)(ch0 + (pp) * 4 + c) * NPTS + it * 256 + lane * 4);          \
    }                                                                            \
  } while (0)

#define WRITET()                                                                 \
  do {                                                                           \
    _Pragma("unroll")                                                            \
    for (int it = 0; it < 4; ++it) {                                             \
      *(float4*)&fw[(256*it + lane) * 4] =                                       \
          make_float4(tile[it][0].x, tile[it][1].x, tile[it][2].x, tile[it][3].x);\
      *(float4*)&fw[(256*it + 64 + lane) * 4] =                                  \
          make_float4(tile[it][0].y, tile[it][1].y, tile[it][2].y, tile[it][3].y);\
      *(float4*)&fw[(256*it + 128 + lane) * 4] =                                 \
          make_float4(tile[it][0].z, tile[it][1].z, tile[it][2].z, tile[it][3].z);\
      *(float4*)&fw[(256*it + 192 + lane) * 4] =                                 \
          make_float4(tile[it][0].w, tile[it][1].w, tile[it][2].w, tile[it][3].w);\
    }                                                                            \
  } while (0)

  LOADT(0);
  WRITET();

  for (int pp = 0; pp < 16; ++pp) {
    if (pp < 15) LOADT(pp + 1);

    float4 o4 = make_float4(0.f, 0.f, 0.f, 0.f);
#pragma unroll
    for (int kk = 0; kk < 16; ++kk) {
      const float4 f4 = *(const float4*)((const char*)fw + jjb[kk]);
      const float ak = a16[kk];
      o4.x = fmaf(ak, f4.x, o4.x);
      o4.y = fmaf(ak, f4.y, o4.y);
      o4.z = fmaf(ak, f4.z, o4.z);
      o4.w = fmaf(ak, f4.w, o4.w);
    }
    o4.x += __shfl_xor(o4.x, 32);
    o4.y += __shfl_xor(o4.y, 32);
    o4.z += __shfl_xor(o4.z, 32);
    o4.w += __shfl_xor(o4.w, 32);

    float* ob = out + ((size_t)batch * DFEAT + ch0 + pp * 4) * NPTS + i0 + row;
    if (khalf == 0) {
      ob[0]            = o4.x;
      ob[(size_t)NPTS] = o4.y;
    } else {
      ob[(size_t)2 * NPTS] = o4.z;
      ob[(size_t)3 * NPTS] = o4.w;
    }

    if (pp < 15) WRITET();
  }
#undef LOADT
#undef WRITET
}

extern "C" void kernel_launch(void* const* d_in, const int* in_sizes, int n_in,
                              void* d_out, int out_size, void* d_ws, size_t ws_size,
                              hipStream_t stream) {
  const float* in = (const float*)d_in[0];
  float* out = (float*)d_out;
  float2* pairs = (float2*)d_ws;                                    // 4 MB
  unsigned short* ph0 = (unsigned short*)((char*)d_ws + (4u << 20)); // 2 MB
  unsigned short* ph1 = (unsigned short*)((char*)d_ws + (6u << 20)); // 2 MB
  unsigned short* ph2 = (unsigned short*)((char*)d_ws + (8u << 20)); // 2 MB
  gnn_phat<<<dim3(64), dim3(256), 0, stream>>>(in, ph0, ph1, ph2);
  gnn_sim_topk<<<dim3(1024), dim3(256), 0, stream>>>(ph0, ph1, ph2, pairs);
  gnn_gather<<<dim3(512), dim3(256), 0, stream>>>(in, pairs, out);
}

// Round 24
// 98.821 us; speedup vs baseline: 1.3767x; 1.3767x over previous
//
#include <hip/hip_runtime.h>
#include <math.h>

#define CT    320
#define NPTS  1024
#define DFEAT 256
#define DPOS  64
#define KSEL  32

// ============ Kernel C: per-point 1/max(||pos||,eps) -> rnjg (ws) ===========
__global__ void gnn_rnj(const float* __restrict__ in, float* __restrict__ rnjg) {
  const int b     = blockIdx.x;
  const int batch = b >> 2;
  const int j     = ((b & 3) << 8) + threadIdx.x;
  const float* __restrict__ pbase = in + (size_t)batch * CT * NPTS + (size_t)DFEAT * NPTS;
  float s = 0.f;
#pragma unroll 8
  for (int d = 0; d < DPOS; ++d) {
    const float x = pbase[(size_t)d * NPTS + j];
    s = fmaf(x, x, s);
  }
  rnjg[batch * NPTS + j] = 1.0f / fmaxf(sqrtf(s), 1e-12f);
}

// ================= Kernel A: round-11 config FROZEN (best: 64 us) ===========
// 1024 blocks; 16 rows/blk; wave owns 4 full rows; triple-buffered jt with
// counted vmcnt(2); 15-bit float-threshold exact top-32 + softmax.
// MFMA alternative tried rounds 21-23: occupancy/VGPR conflict is infeasible
// (93 us / numerics-fail / 103 us+spill). f32 VALU sim is the right tool here.
#define AROWS 16
#define DCH   2
#define QSTEP 6.103515625e-05f          // 2^-14, thr(m) = m*QSTEP - 1 (exact)
__global__ __launch_bounds__(256, 4) void gnn_sim_topk(const float* __restrict__ in,
                                                       const float* __restrict__ rnjg,
                                                       float2* __restrict__ pairs) {
  __shared__ float pi[DPOS * 20];
  __shared__ float rnjL[NPTS];
  __shared__ float jt[3][DCH * 1024];
  __shared__ float cand[AROWS][68];

  const int p     = blockIdx.x;
  const int batch = ((p & 7) << 1) | ((p >> 3) & 1);
  const int chunk = p >> 4;
  const int i0    = chunk * AROWS;
  const int tid   = threadIdx.x;
  const int w     = tid >> 6;
  const int lane  = tid & 63;

  const float* __restrict__ pbase = in + (size_t)batch * CT * NPTS + (size_t)DFEAT * NPTS;

  {
    const int i = tid & 15;
    const int d0 = tid >> 4;
#pragma unroll
    for (int pass = 0; pass < 4; ++pass) {
      const int d = pass * 16 + d0;
      pi[d * 20 + i] = pbase[(size_t)d * NPTS + i0 + i];
    }
  }
  *(float4*)&rnjL[tid * 4] = *(const float4*)&rnjg[batch * NPTS + tid * 4];

#define JSTAGE(buf, c)                                                           \
  do {                                                                           \
    const int dd_   = (w >> 1);                                                  \
    const int half_ = (w & 1);                                                   \
    const float* src_ = pbase + (size_t)((c) * DCH + dd_) * NPTS + half_ * 512 + lane * 4; \
    float* dst_ = &jt[buf][dd_ * 1024 + half_ * 512];                            \
    __builtin_amdgcn_global_load_lds(                                            \
        (const __attribute__((address_space(1))) void*)(src_),                   \
        (__attribute__((address_space(3))) void*)(dst_), 16, 0, 0);              \
    __builtin_amdgcn_global_load_lds(                                            \
        (const __attribute__((address_space(1))) void*)(src_ + 256),             \
        (__attribute__((address_space(3))) void*)(dst_ + 256), 16, 0, 0);        \
  } while (0)

  JSTAGE(0, 0);
  JSTAGE(1, 1);
  asm volatile("s_waitcnt vmcnt(2)" ::: "memory");
  __syncthreads();

  float acc[4][16];
#pragma unroll
  for (int r = 0; r < 4; ++r)
#pragma unroll
    for (int s = 0; s < 16; ++s) acc[r][s] = 0.f;

  int cur = 0;
  for (int c = 0; c < DPOS / DCH; ++c) {
#pragma unroll
    for (int dd = 0; dd < DCH; ++dd) {
      const int d = c * DCH + dd;
      const float4 pv4 = *(const float4*)&pi[d * 20 + w * 4];
      const float pr_[4] = {pv4.x, pv4.y, pv4.z, pv4.w};
      float4 jv[4];
#pragma unroll
      for (int u = 0; u < 4; ++u)
        jv[u] = *(const float4*)&jt[cur][dd * 1024 + u * 256 + lane * 4];
#pragma unroll
      for (int r = 0; r < 4; ++r) {
#pragma unroll
        for (int u = 0; u < 4; ++u) {
          acc[r][u*4+0] = fmaf(pr_[r], jv[u].x, acc[r][u*4+0]);
          acc[r][u*4+1] = fmaf(pr_[r], jv[u].y, acc[r][u*4+1]);
          acc[r][u*4+2] = fmaf(pr_[r], jv[u].z, acc[r][u*4+2]);
          acc[r][u*4+3] = fmaf(pr_[r], jv[u].w, acc[r][u*4+3]);
        }
      }
    }
    if (c < DPOS / DCH - 2) {
      const int nbuf = (cur + 2 >= 3) ? cur - 1 : cur + 2;
      JSTAGE(nbuf, c + 2);
      asm volatile("s_waitcnt vmcnt(2)" ::: "memory");
    } else {
      asm volatile("s_waitcnt vmcnt(0)" ::: "memory");
    }
    __syncthreads();
    cur = (cur + 1 >= 3) ? 0 : cur + 1;
  }
#undef JSTAGE

  float4 rv[4];
#pragma unroll
  for (int u = 0; u < 4; ++u) rv[u] = *(const float4*)&rnjL[u * 256 + lane * 4];

#pragma unroll
  for (int r = 0; r < 4; ++r) {
    const int rglob = w * 4 + r;
    const float sc = rnjL[i0 + rglob];
    float v[16];
#pragma unroll
    for (int u = 0; u < 4; ++u) {
      v[u*4+0] = acc[r][u*4+0] * rv[u].x * sc;
      v[u*4+1] = acc[r][u*4+1] * rv[u].y * sc;
      v[u*4+2] = acc[r][u*4+2] * rv[u].z * sc;
      v[u*4+3] = acc[r][u*4+3] * rv[u].w * sc;
    }
    int lo = 0;
#pragma unroll
    for (int bit = 16384; bit >= 1; bit >>= 1) {
      const float thrf = (float)(lo + bit) * QSTEP - 1.0f;
      int cnt = 0;
#pragma unroll
      for (int t = 0; t < 16; ++t) cnt += (int)__popcll(__ballot(v[t] >= thrf));
      if (cnt >= KSEL) lo += bit;
    }
    const float thr_h = (float)(lo + 1) * QSTEP - 1.0f;
    const float thr_l = (float)lo * QSTEP - 1.0f;
    int cbase = 0;
    unsigned cmask = 0u;
#pragma unroll
    for (int t = 0; t < 16; ++t) {
      const bool hi = (v[t] >= thr_h);
      const unsigned long long m = __ballot(hi);
      if (hi) {
        const int pos = cbase + (int)__builtin_amdgcn_mbcnt_hi(
            (unsigned)(m >> 32), __builtin_amdgcn_mbcnt_lo((unsigned)m, 0u));
        const int j = (t >> 2) * 256 + lane * 4 + (t & 3);
        *(float2*)&cand[rglob][2 * pos] = make_float2(v[t], __int_as_float(j));
      }
      cbase += (int)__popcll(m);
      if ((v[t] >= thr_l) && !hi) cmask |= (1u << t);
    }
    const int need = KSEL - cbase;
    for (int it = 0; it < need; ++it) {
      float bv = -2.0f; int bj = 0x7fffffff; int bt = 16;
#pragma unroll
      for (int t = 0; t < 16; ++t) {
        if (((cmask >> t) & 1u) && v[t] > bv) {
          bv = v[t]; bj = (t >> 2) * 256 + lane * 4 + (t & 3); bt = t;
        }
      }
      float rvv = bv; int rj = bj;
#pragma unroll
      for (int s = 1; s < 64; s <<= 1) {
        const float ov = __shfl_xor(rvv, s);
        const int   oj = __shfl_xor(rj, s);
        if (ov > rvv || (ov == rvv && oj < rj)) { rvv = ov; rj = oj; }
      }
      if (bv == rvv && bj == rj) {
        *(float2*)&cand[rglob][2 * (cbase + it)] = make_float2(bv, __int_as_float(bj));
        cmask &= ~(1u << bt);
      }
    }
    {
      const float x = cand[rglob][2 * (lane & 31)];
      float mx = x;
#pragma unroll
      for (int s = 16; s >= 1; s >>= 1) mx = fmaxf(mx, __shfl_xor(mx, s));
      const float e = expf(x - mx);
      float sum = e;
#pragma unroll
      for (int s = 16; s >= 1; s >>= 1) sum += __shfl_xor(sum, s);
      if (lane < KSEL) cand[rglob][2 * lane] = e / sum;
    }
  }
  __syncthreads();

  {
    const int pidx = tid * 2;
    const int r = pidx >> 5, k = pidx & 31;
    const float4 o4 = *(const float4*)&cand[r][2 * k];
    *(float4*)&pairs[((size_t)batch * NPTS + i0 + r) * KSEL + k] = o4;
  }
}

// ====== Kernel B: transposed-LDS float4 gather (round-20 proven, frozen) ====
__global__ __launch_bounds__(256, 2) void gnn_gather(const float* __restrict__ in,
                                                     const float2* __restrict__ pairs,
                                                     float* __restrict__ out) {
  __shared__ float fst[4][4096];       // per-wave 16 KB: 1024 granules x 16B

  const int p     = blockIdx.x;
  const int batch = ((p & 7) << 1) | ((p >> 3) & 1);
  const int chunk = p >> 4;            // 0..31
  const int i0    = chunk * 32;
  const int tid   = threadIdx.x;
  const int w     = tid >> 6;
  const int lane  = tid & 63;
  const int row   = lane & 31;
  const int khalf = lane >> 5;
  const int ch0   = w * 64;

  const float* __restrict__ fbase = in + (size_t)batch * CT * NPTS;
  float* const fw = &fst[w][0];

  float a16[16]; int jjb[16];
  {
    const float4* pr4 = (const float4*)(pairs + ((size_t)batch * NPTS + i0 + row) * KSEL)
                        + khalf * 8;
#pragma unroll
    for (int qq = 0; qq < 8; ++qq) {
      const float4 o = pr4[qq];
      const int id0 = __float_as_int(o.y);
      const int id1 = __float_as_int(o.w);
      a16[2*qq]   = o.x;
      jjb[2*qq]   = ((((id0 & 3) << 6) | ((id0 >> 2) & 63) | (id0 & ~255)) << 4);
      a16[2*qq+1] = o.z;
      jjb[2*qq+1] = ((((id1 & 3) << 6) | ((id1 >> 2) & 63) | (id1 & ~255)) << 4);
    }
  }

  float4 tile[4][4];

#define LOADT(pp)                                                                \
  do {                                                                           \
    _Pragma("unroll")                                                            \
    for (int it = 0; it < 4; ++it) {                                             \
      _Pragma("unroll")                                                          \
      for (int c = 0; c < 4; ++c)                                                \
        tile[it][c] = *(const float4*)(fbase +                                   \
            (size_t)(ch0 + (pp) * 4 + c) * NPTS + it * 256 + lane * 4);          \
    }                                                                            \
  } while (0)

#define WRITET()                                                                 \
  do {                                                                           \
    _Pragma("unroll")                                                            \
    for (int it = 0; it < 4; ++it) {                                             \
      *(float4*)&fw[(256*it + lane) * 4] =                                       \
          make_float4(tile[it][0].x, tile[it][1].x, tile[it][2].x, tile[it][3].x);\
      *(float4*)&fw[(256*it + 64 + lane) * 4] =                                  \
          make_float4(tile[it][0].y, tile[it][1].y, tile[it][2].y, tile[it][3].y);\
      *(float4*)&fw[(256*it + 128 + lane) * 4] =                                 \
          make_float4(tile[it][0].z, tile[it][1].z, tile[it][2].z, tile[it][3].z);\
      *(float4*)&fw[(256*it + 192 + lane) * 4] =                                 \
          make_float4(tile[it][0].w, tile[it][1].w, tile[it][2].w, tile[it][3].w);\
    }                                                                            \
  } while (0)

  LOADT(0);
  WRITET();

  for (int pp = 0; pp < 16; ++pp) {
    if (pp < 15) LOADT(pp + 1);

    float4 o4 = make_float4(0.f, 0.f, 0.f, 0.f);
#pragma unroll
    for (int kk = 0; kk < 16; ++kk) {
      const float4 f4 = *(const float4*)((const char*)fw + jjb[kk]);
      const float ak = a16[kk];
      o4.x = fmaf(ak, f4.x, o4.x);
      o4.y = fmaf(ak, f4.y, o4.y);
      o4.z = fmaf(ak, f4.z, o4.z);
      o4.w = fmaf(ak, f4.w, o4.w);
    }
    o4.x += __shfl_xor(o4.x, 32);
    o4.y += __shfl_xor(o4.y, 32);
    o4.z += __shfl_xor(o4.z, 32);
    o4.w += __shfl_xor(o4.w, 32);

    float* ob = out + ((size_t)batch * DFEAT + ch0 + pp * 4) * NPTS + i0 + row;
    if (khalf == 0) {
      ob[0]            = o4.x;
      ob[(size_t)NPTS] = o4.y;
    } else {
      ob[(size_t)2 * NPTS] = o4.z;
      ob[(size_t)3 * NPTS] = o4.w;
    }

    if (pp < 15) WRITET();
  }
#undef LOADT
#undef WRITET
}

extern "C" void kernel_launch(void* const* d_in, const int* in_sizes, int n_in,
                              void* d_out, int out_size, void* d_ws, size_t ws_size,
                              hipStream_t stream) {
  const float* in = (const float*)d_in[0];
  float* out = (float*)d_out;
  float2* pairs = (float2*)d_ws;                           // 4 MB
  float*  rnjg  = (float*)((char*)d_ws + (16u << 20) / 4); // +4 MB: 64 KB table
  gnn_rnj<<<dim3(64), dim3(256), 0, stream>>>(in, rnjg);
  gnn_sim_topk<<<dim3(1024), dim3(256), 0, stream>>>(in, rnjg, pairs);
  gnn_gather<<<dim3(512), dim3(256), 0, stream>>>(in, pairs, out);
}

// Round 25
// 94.124 us; speedup vs baseline: 1.4454x; 1.0499x over previous
//
#include <hip/hip_runtime.h>
#include <math.h>

#define CT    320
#define NPTS  1024
#define DFEAT 256
#define DPOS  64
#define KSEL  32

// ============ Kernel C: per-point 1/max(||pos||,eps) -> rnjg (ws) ===========
__global__ void gnn_rnj(const float* __restrict__ in, float* __restrict__ rnjg) {
  const int b     = blockIdx.x;
  const int batch = b >> 2;
  const int j     = ((b & 3) << 8) + threadIdx.x;
  const float* __restrict__ pbase = in + (size_t)batch * CT * NPTS + (size_t)DFEAT * NPTS;
  float s = 0.f;
#pragma unroll 8
  for (int d = 0; d < DPOS; ++d) {
    const float x = pbase[(size_t)d * NPTS + j];
    s = fmaf(x, x, s);
  }
  rnjg[batch * NPTS + j] = 1.0f / fmaxf(sqrtf(s), 1e-12f);
}

// ================= Kernel A: round-11 config FROZEN (best: 64 us) ===========
#define AROWS 16
#define DCH   2
#define QSTEP 6.103515625e-05f          // 2^-14, thr(m) = m*QSTEP - 1 (exact)
__global__ __launch_bounds__(256, 4) void gnn_sim_topk(const float* __restrict__ in,
                                                       const float* __restrict__ rnjg,
                                                       float2* __restrict__ pairs) {
  __shared__ float pi[DPOS * 20];
  __shared__ float rnjL[NPTS];
  __shared__ float jt[3][DCH * 1024];
  __shared__ float cand[AROWS][68];

  const int p     = blockIdx.x;
  const int batch = ((p & 7) << 1) | ((p >> 3) & 1);
  const int chunk = p >> 4;
  const int i0    = chunk * AROWS;
  const int tid   = threadIdx.x;
  const int w     = tid >> 6;
  const int lane  = tid & 63;

  const float* __restrict__ pbase = in + (size_t)batch * CT * NPTS + (size_t)DFEAT * NPTS;

  {
    const int i = tid & 15;
    const int d0 = tid >> 4;
#pragma unroll
    for (int pass = 0; pass < 4; ++pass) {
      const int d = pass * 16 + d0;
      pi[d * 20 + i] = pbase[(size_t)d * NPTS + i0 + i];
    }
  }
  *(float4*)&rnjL[tid * 4] = *(const float4*)&rnjg[batch * NPTS + tid * 4];

#define JSTAGE(buf, c)                                                           \
  do {                                                                           \
    const int dd_   = (w >> 1);                                                  \
    const int half_ = (w & 1);                                                   \
    const float* src_ = pbase + (size_t)((c) * DCH + dd_) * NPTS + half_ * 512 + lane * 4; \
    float* dst_ = &jt[buf][dd_ * 1024 + half_ * 512];                            \
    __builtin_amdgcn_global_load_lds(                                            \
        (const __attribute__((address_space(1))) void*)(src_),                   \
        (__attribute__((address_space(3))) void*)(dst_), 16, 0, 0);              \
    __builtin_amdgcn_global_load_lds(                                            \
        (const __attribute__((address_space(1))) void*)(src_ + 256),             \
        (__attribute__((address_space(3))) void*)(dst_ + 256), 16, 0, 0);        \
  } while (0)

  JSTAGE(0, 0);
  JSTAGE(1, 1);
  asm volatile("s_waitcnt vmcnt(2)" ::: "memory");
  __syncthreads();

  float acc[4][16];
#pragma unroll
  for (int r = 0; r < 4; ++r)
#pragma unroll
    for (int s = 0; s < 16; ++s) acc[r][s] = 0.f;

  int cur = 0;
  for (int c = 0; c < DPOS / DCH; ++c) {
#pragma unroll
    for (int dd = 0; dd < DCH; ++dd) {
      const int d = c * DCH + dd;
      const float4 pv4 = *(const float4*)&pi[d * 20 + w * 4];
      const float pr_[4] = {pv4.x, pv4.y, pv4.z, pv4.w};
      float4 jv[4];
#pragma unroll
      for (int u = 0; u < 4; ++u)
        jv[u] = *(const float4*)&jt[cur][dd * 1024 + u * 256 + lane * 4];
#pragma unroll
      for (int r = 0; r < 4; ++r) {
#pragma unroll
        for (int u = 0; u < 4; ++u) {
          acc[r][u*4+0] = fmaf(pr_[r], jv[u].x, acc[r][u*4+0]);
          acc[r][u*4+1] = fmaf(pr_[r], jv[u].y, acc[r][u*4+1]);
          acc[r][u*4+2] = fmaf(pr_[r], jv[u].z, acc[r][u*4+2]);
          acc[r][u*4+3] = fmaf(pr_[r], jv[u].w, acc[r][u*4+3]);
        }
      }
    }
    if (c < DPOS / DCH - 2) {
      const int nbuf = (cur + 2 >= 3) ? cur - 1 : cur + 2;
      JSTAGE(nbuf, c + 2);
      asm volatile("s_waitcnt vmcnt(2)" ::: "memory");
    } else {
      asm volatile("s_waitcnt vmcnt(0)" ::: "memory");
    }
    __syncthreads();
    cur = (cur + 1 >= 3) ? 0 : cur + 1;
  }
#undef JSTAGE

  float4 rv[4];
#pragma unroll
  for (int u = 0; u < 4; ++u) rv[u] = *(const float4*)&rnjL[u * 256 + lane * 4];

#pragma unroll
  for (int r = 0; r < 4; ++r) {
    const int rglob = w * 4 + r;
    const float sc = rnjL[i0 + rglob];
    float v[16];
#pragma unroll
    for (int u = 0; u < 4; ++u) {
      v[u*4+0] = acc[r][u*4+0] * rv[u].x * sc;
      v[u*4+1] = acc[r][u*4+1] * rv[u].y * sc;
      v[u*4+2] = acc[r][u*4+2] * rv[u].z * sc;
      v[u*4+3] = acc[r][u*4+3] * rv[u].w * sc;
    }
    int lo = 0;
#pragma unroll
    for (int bit = 16384; bit >= 1; bit >>= 1) {
      const float thrf = (float)(lo + bit) * QSTEP - 1.0f;
      int cnt = 0;
#pragma unroll
      for (int t = 0; t < 16; ++t) cnt += (int)__popcll(__ballot(v[t] >= thrf));
      if (cnt >= KSEL) lo += bit;
    }
    const float thr_h = (float)(lo + 1) * QSTEP - 1.0f;
    const float thr_l = (float)lo * QSTEP - 1.0f;
    int cbase = 0;
    unsigned cmask = 0u;
#pragma unroll
    for (int t = 0; t < 16; ++t) {
      const bool hi = (v[t] >= thr_h);
      const unsigned long long m = __ballot(hi);
      if (hi) {
        const int pos = cbase + (int)__builtin_amdgcn_mbcnt_hi(
            (unsigned)(m >> 32), __builtin_amdgcn_mbcnt_lo((unsigned)m, 0u));
        const int j = (t >> 2) * 256 + lane * 4 + (t & 3);
        *(float2*)&cand[rglob][2 * pos] = make_float2(v[t], __int_as_float(j));
      }
      cbase += (int)__popcll(m);
      if ((v[t] >= thr_l) && !hi) cmask |= (1u << t);
    }
    const int need = KSEL - cbase;
    for (int it = 0; it < need; ++it) {
      float bv = -2.0f; int bj = 0x7fffffff; int bt = 16;
#pragma unroll
      for (int t = 0; t < 16; ++t) {
        if (((cmask >> t) & 1u) && v[t] > bv) {
          bv = v[t]; bj = (t >> 2) * 256 + lane * 4 + (t & 3); bt = t;
        }
      }
      float rvv = bv; int rj = bj;
#pragma unroll
      for (int s = 1; s < 64; s <<= 1) {
        const float ov = __shfl_xor(rvv, s);
        const int   oj = __shfl_xor(rj, s);
        if (ov > rvv || (ov == rvv && oj < rj)) { rvv = ov; rj = oj; }
      }
      if (bv == rvv && bj == rj) {
        *(float2*)&cand[rglob][2 * (cbase + it)] = make_float2(bv, __int_as_float(bj));
        cmask &= ~(1u << bt);
      }
    }
    {
      const float x = cand[rglob][2 * (lane & 31)];
      float mx = x;
#pragma unroll
      for (int s = 16; s >= 1; s >>= 1) mx = fmaxf(mx, __shfl_xor(mx, s));
      const float e = expf(x - mx);
      float sum = e;
#pragma unroll
      for (int s = 16; s >= 1; s >>= 1) sum += __shfl_xor(sum, s);
      if (lane < KSEL) cand[rglob][2 * lane] = e / sum;
    }
  }
  __syncthreads();

  {
    const int pidx = tid * 2;
    const int r = pidx >> 5, k = pidx & 31;
    const float4 o4 = *(const float4*)&cand[r][2 * k];
    *(float4*)&pairs[((size_t)batch * NPTS + i0 + r) * KSEL + k] = o4;
  }
}

// ====== Kernel B: transposed-LDS gather, 64 rows/block (round-25) ==========
// 512 blocks = 16 batch x 16 rowchunk x 2 chalf. Block owns 64 rows x 128
// channels; wave owns 32 channels, 8 passes of 4. Each lane gathers TWO
// row-slots (rs, rs+32) against the same staged tile -> staging amortized
// over 2x outputs: L2 staging traffic 512 MB -> 256 MB. Gather reads/lane
// unchanged (8x32 = 16x16). Transposed granule layout + khalf k-split
// identical to round-20 (proven).
__global__ __launch_bounds__(256, 2) void gnn_gather(const float* __restrict__ in,
                                                     const float2* __restrict__ pairs,
                                                     float* __restrict__ out) {
  __shared__ float fst[4][4096];       // per-wave 16 KB: 1024 granules x 16B

  const int p     = blockIdx.x;
  const int batch = ((p & 7) << 1) | ((p >> 3) & 1);   // 2 batches per XCD
  const int chunk = p >> 4;            // 0..31
  const int rchk  = chunk >> 1;        // 0..15 (64-row chunk)
  const int chalf = chunk & 1;         // channel half
  const int i0    = rchk * 64;
  const int tid   = threadIdx.x;
  const int w     = tid >> 6;
  const int lane  = tid & 63;
  const int rs    = lane & 31;         // row slot: rows i0+rs, i0+32+rs
  const int khalf = lane >> 5;
  const int ch0   = chalf * 128 + w * 32;   // wave's 32 channels

  const float* __restrict__ fbase = in + (size_t)batch * CT * NPTS;
  float* const fw = &fst[w][0];

  // pairs for both row-slots (khalf's 16 k each), swizzled byte offsets
  float aA[16], aB[16]; int jA[16], jB[16];
  {
    const float4* prA = (const float4*)(pairs + ((size_t)batch * NPTS + i0 + rs) * KSEL)
                        + khalf * 8;
    const float4* prB = (const float4*)(pairs + ((size_t)batch * NPTS + i0 + 32 + rs) * KSEL)
                        + khalf * 8;
#pragma unroll
    for (int qq = 0; qq < 8; ++qq) {
      const float4 oA = prA[qq];
      const float4 oB = prB[qq];
      const int a0 = __float_as_int(oA.y), a1 = __float_as_int(oA.w);
      const int b0 = __float_as_int(oB.y), b1 = __float_as_int(oB.w);
      aA[2*qq]   = oA.x; jA[2*qq]   = ((((a0 & 3) << 6) | ((a0 >> 2) & 63) | (a0 & ~255)) << 4);
      aA[2*qq+1] = oA.z; jA[2*qq+1] = ((((a1 & 3) << 6) | ((a1 >> 2) & 63) | (a1 & ~255)) << 4);
      aB[2*qq]   = oB.x; jB[2*qq]   = ((((b0 & 3) << 6) | ((b0 >> 2) & 63) | (b0 & ~255)) << 4);
      aB[2*qq+1] = oB.z; jB[2*qq+1] = ((((b1 & 3) << 6) | ((b1 >> 2) & 63) | (b1 & ~255)) << 4);
    }
  }

  float4 tile[4][4];                   // [it][c], all indices compile-time

#define LOADT(pp)                                                                \
  do {                                                                           \
    _Pragma("unroll")                                                            \
    for (int it = 0; it < 4; ++it) {                                             \
      _Pragma("unroll")                                                          \
      for (int c = 0; c < 4; ++c)                                                \
        tile[it][c] = *(const float4*)(fbase +                                   \
            (size_t)(ch0 + (pp) * 4 + c) * NPTS + it * 256 + lane * 4);          \
    }                                                                            \
  } while (0)

#define WRITET()                                                                 \
  do {                                                                           \
    _Pragma("unroll")                                                            \
    for (int it = 0; it < 4; ++it) {                                             \
      *(float4*)&fw[(256*it + lane) * 4] =                                       \
          make_float4(tile[it][0].x, tile[it][1].x, tile[it][2].x, tile[it][3].x);\
      *(float4*)&fw[(256*it + 64 + lane) * 4] =                                  \
          make_float4(tile[it][0].y, tile[it][1].y, tile[it][2].y, tile[it][3].y);\
      *(float4*)&fw[(256*it + 128 + lane) * 4] =                                 \
          make_float4(tile[it][0].z, tile[it][1].z, tile[it][2].z, tile[it][3].z);\
      *(float4*)&fw[(256*it + 192 + lane) * 4] =                                 \
          make_float4(tile[it][0].w, tile[it][1].w, tile[it][2].w, tile[it][3].w);\
    }                                                                            \
  } while (0)

  LOADT(0);
  WRITET();                            // compiler waits loads before first use

  for (int pp = 0; pp < 8; ++pp) {
    if (pp < 7) LOADT(pp + 1);         // issue next tile early (T14)

    float4 oA4 = make_float4(0.f, 0.f, 0.f, 0.f);
    float4 oB4 = make_float4(0.f, 0.f, 0.f, 0.f);
#pragma unroll
    for (int kk = 0; kk < 16; ++kk) {
      const float4 fA = *(const float4*)((const char*)fw + jA[kk]);
      const float ak = aA[kk];
      oA4.x = fmaf(ak, fA.x, oA4.x);
      oA4.y = fmaf(ak, fA.y, oA4.y);
      oA4.z = fmaf(ak, fA.z, oA4.z);
      oA4.w = fmaf(ak, fA.w, oA4.w);
    }
#pragma unroll
    for (int kk = 0; kk < 16; ++kk) {
      const float4 fB = *(const float4*)((const char*)fw + jB[kk]);
      const float bk = aB[kk];
      oB4.x = fmaf(bk, fB.x, oB4.x);
      oB4.y = fmaf(bk, fB.y, oB4.y);
      oB4.z = fmaf(bk, fB.z, oB4.z);
      oB4.w = fmaf(bk, fB.w, oB4.w);
    }
    // combine k-halves (lane <-> lane+32, same rs); k order lo+hi as round-20
    oA4.x += __shfl_xor(oA4.x, 32);
    oA4.y += __shfl_xor(oA4.y, 32);
    oA4.z += __shfl_xor(oA4.z, 32);
    oA4.w += __shfl_xor(oA4.w, 32);
    oB4.x += __shfl_xor(oB4.x, 32);
    oB4.y += __shfl_xor(oB4.y, 32);
    oB4.z += __shfl_xor(oB4.z, 32);
    oB4.w += __shfl_xor(oB4.w, 32);

    float* obA = out + ((size_t)batch * DFEAT + ch0 + pp * 4) * NPTS + i0 + rs;
    float* obB = obA + 32;
    if (khalf == 0) {
      obA[0]            = oA4.x;
      obA[(size_t)NPTS] = oA4.y;
      obB[0]            = oB4.x;
      obB[(size_t)NPTS] = oB4.y;
    } else {
      obA[(size_t)2 * NPTS] = oA4.z;
      obA[(size_t)3 * NPTS] = oA4.w;
      obB[(size_t)2 * NPTS] = oB4.z;
      obB[(size_t)3 * NPTS] = oB4.w;
    }

    if (pp < 7) WRITET();              // LDS write after gather reads (in-order DS)
  }
#undef LOADT
#undef WRITET
}

extern "C" void kernel_launch(void* const* d_in, const int* in_sizes, int n_in,
                              void* d_out, int out_size, void* d_ws, size_t ws_size,
                              hipStream_t stream) {
  const float* in = (const float*)d_in[0];
  float* out = (float*)d_out;
  float2* pairs = (float2*)d_ws;                           // 4 MB
  float*  rnjg  = (float*)((char*)d_ws + (16u << 20) / 4); // +4 MB: 64 KB table
  gnn_rnj<<<dim3(64), dim3(256), 0, stream>>>(in, rnjg);
  gnn_sim_topk<<<dim3(1024), dim3(256), 0, stream>>>(in, rnjg, pairs);
  gnn_gather<<<dim3(512), dim3(256), 0, stream>>>(in, pairs, out);
}